// Round 7
// baseline (78.200 us; speedup 1.0000x reference)
//
#include <hip/hip_runtime.h>
#include <hip/hip_fp16.h>

// NCC (local normalized cross-correlation) loss, 9x9x9 window, zero-pad.
// Volume: [1,1,128,160,192] f32. Output: scalar f32 = 1 - mean(cc).
//
// R7: two-kernel structure.
//  K1 (fused pass1+pass2): thread ~ (group, d, h-run, wp-pair). Per row:
//     masked float2 loads of the I/J row halo (w0-4..w0+5), W-sums of the
//     group's channels in registers, 9-deep H-FIFO -> write B (half2) only.
//     Groups: g0: I -> {ch0=I, ch2=I2}; g1: J -> {ch1=J, ch3=J2}; g2: IJ -> ch4.
//     The A intermediate (39MB W + 48MB R) is gone.
//  K2 (pass3): D-axis reload sliding window + cc + atomic reduce (from R6).
//  finalize: out = 1 - acc/N.
// ws: B 5*N/2 half2 + acc = 39.3 MB.

#define D_ 128
#define H_ 160
#define W_ 192
#define WP_ (W_ / 2)               // 96 half2 per line
#define HW_ (H_ * W_)
#define HWP_ (HW_ / 2)             // half2 per d-slice
#define N_ (D_ * H_ * W_)          // 3,932,160
#define NH2 (N_ / 2)               // half2 per channel
#define WIN_INV (1.0f / 729.0f)
#define HR 20                      // h-run length in K1 (8 chunks)
#define CH3 8                      // d-run length in K2

__device__ __forceinline__ __half2 f2h(float x, float y) {
    return __float22half2_rn(make_float2(x, y));
}
__device__ __forceinline__ float2 h2f(__half2 v) { return __half22float2(v); }

// ------------------- K1: fused W-sum + H-sum -> B ------------------------
__global__ __launch_bounds__(256) void ncc_k1(const float* __restrict__ I,
                                              const float* __restrict__ J,
                                              __half2* __restrict__ B,
                                              float* __restrict__ acc) {
    if (blockIdx.x == 0 && threadIdx.x == 0) *acc = 0.0f;
    const int t = blockIdx.x * 256 + threadIdx.x;   // < 3*128*8*96 = 294912
    const int wp = t % WP_;
    int r = t / WP_;
    const int hc = r & 7;  r >>= 3;
    const int d  = r & 127; r >>= 7;
    const int g  = r;                                // 0,1,2 (wave-uniform)
    const int w0 = 2 * wp;
    const int h0 = hc * HR;
    const float* __restrict__ PA = (g == 1 ? J : I) + (size_t)d * HW_;
    const float* __restrict__ PB = J + (size_t)d * HW_;

    const size_t obase = (size_t)d * (H_ * WP_) + wp;
    __half2* out0;
    __half2* out1 = nullptr;
    if (g == 0)      { out0 = B + 0 * NH2 + obase; out1 = B + 2 * NH2 + obase; }
    else if (g == 1) { out0 = B + 1 * NH2 + obase; out1 = B + 3 * NH2 + obase; }
    else             { out0 = B + 4 * NH2 + obase; }

    float2 win0[9], win1[9];
    float2 S0 = make_float2(0.f, 0.f), S1 = make_float2(0.f, 0.f);

    // W-sums of this thread's channels at row h -> o0 (ch A), o1 (ch B).
    auto rowsum = [&](int h, float2& o0, float2& o1) {
        o0 = make_float2(0.f, 0.f);
        o1 = make_float2(0.f, 0.f);
        if ((unsigned)h >= (unsigned)H_) return;     // zero-pad row
        const float* ra = PA + h * W_;
        float a[10];
#pragma unroll
        for (int k = 0; k < 5; ++k) {
            int idx = w0 - 4 + 2 * k;
            float2 v = make_float2(0.f, 0.f);
            if ((unsigned)idx < (unsigned)(W_ - 1)) v = *(const float2*)(ra + idx);
            a[2 * k] = v.x; a[2 * k + 1] = v.y;
        }
        if (g == 2) {
            const float* rb = PB + h * W_;
            float p[10];
#pragma unroll
            for (int k = 0; k < 5; ++k) {
                int idx = w0 - 4 + 2 * k;
                float2 v = make_float2(0.f, 0.f);
                if ((unsigned)idx < (unsigned)(W_ - 1)) v = *(const float2*)(rb + idx);
                p[2 * k] = a[2 * k] * v.x; p[2 * k + 1] = a[2 * k + 1] * v.y;
            }
            float sx = 0.f;
#pragma unroll
            for (int j = 0; j < 9; ++j) sx += p[j];
            o0 = make_float2(sx, sx - p[0] + p[9]);
        } else {
            float sx = 0.f, qx = 0.f;
#pragma unroll
            for (int j = 0; j < 9; ++j) { sx += a[j]; qx += a[j] * a[j]; }
            o0 = make_float2(sx, sx - a[0] + a[9]);
            o1 = make_float2(qx, qx - a[0] * a[0] + a[9] * a[9]);
        }
    };

    // FIFO warm-up: rows h0-4 .. h0+4
#pragma unroll
    for (int j = 0; j < 9; ++j) {
        float2 o0, o1;
        rowsum(h0 - 4 + j, o0, o1);
        win0[j] = o0; win1[j] = o1;
        S0.x += o0.x; S0.y += o0.y; S1.x += o1.x; S1.y += o1.y;
    }
    // main run
#pragma unroll
    for (int i = 0; i < HR; ++i) {
        const int h = h0 + i;
        out0[h * WP_] = f2h(S0.x, S0.y);
        if (g != 2) out1[h * WP_] = f2h(S1.x, S1.y);
        if (i + 1 < HR) {
            float2 o0, o1;
            rowsum(h + 5, o0, o1);
            S0.x += o0.x - win0[0].x; S0.y += o0.y - win0[0].y;
            S1.x += o1.x - win1[0].x; S1.y += o1.y - win1[0].y;
#pragma unroll
            for (int j = 0; j < 8; ++j) { win0[j] = win0[j + 1]; win1[j] = win1[j + 1]; }
            win0[8] = o0; win1[8] = o1;
        }
    }
}

// ---- K2: D-axis box sum + cc + reduce, reload sliding window (R6) --------
__global__ __launch_bounds__(256) void ncc_k2(const __half2* __restrict__ B,
                                              float* __restrict__ acc) {
    const int pp = (blockIdx.x % (HWP_ / 256)) * 256 + threadIdx.x;
    const int d0 = (blockIdx.x / (HWP_ / 256)) * CH3;
    const __half2* base = B + pp;

    float2 S[5];
    float sum = 0.f;
#pragma unroll
    for (int c = 0; c < 5; ++c) S[c] = make_float2(0.f, 0.f);
#pragma unroll
    for (int j = -4; j <= 4; ++j) {
        int dd = d0 + j;
        if ((unsigned)dd < (unsigned)D_) {
#pragma unroll
            for (int c = 0; c < 5; ++c) {
                float2 v = h2f(base[c * NH2 + dd * HWP_]);
                S[c].x += v.x; S[c].y += v.y;
            }
        }
    }
#pragma unroll
    for (int i = 0; i < CH3; ++i) {
        {
            float cr = S[4].x - S[1].x * S[0].x * WIN_INV;
            float Iv = S[2].x - S[0].x * S[0].x * WIN_INV;
            float Jv = S[3].x - S[1].x * S[1].x * WIN_INV;
            sum += cr * cr / (Iv * Jv + 1e-5f);
        }
        {
            float cr = S[4].y - S[1].y * S[0].y * WIN_INV;
            float Iv = S[2].y - S[0].y * S[0].y * WIN_INV;
            float Jv = S[3].y - S[1].y * S[1].y * WIN_INV;
            sum += cr * cr / (Iv * Jv + 1e-5f);
        }
        if (i + 1 < CH3) {
            int dl = d0 + i + 5;
            int dt = d0 + i - 4;
            if (dl < D_) {
#pragma unroll
                for (int c = 0; c < 5; ++c) {
                    float2 v = h2f(base[c * NH2 + dl * HWP_]);
                    S[c].x += v.x; S[c].y += v.y;
                }
            }
            if (dt >= 0) {
#pragma unroll
                for (int c = 0; c < 5; ++c) {
                    float2 v = h2f(base[c * NH2 + dt * HWP_]);
                    S[c].x -= v.x; S[c].y -= v.y;
                }
            }
        }
    }

    for (int off = 32; off; off >>= 1) sum += __shfl_down(sum, off, 64);
    __shared__ float wsum[4];
    const int lane = threadIdx.x & 63, wv = threadIdx.x >> 6;
    if (lane == 0) wsum[wv] = sum;
    __syncthreads();
    if (threadIdx.x == 0)
        atomicAdd(acc, wsum[0] + wsum[1] + wsum[2] + wsum[3]);
}

__global__ void ncc_finalize(const float* __restrict__ acc,
                             float* __restrict__ out) {
    out[0] = 1.0f - acc[0] * (1.0f / (float)N_);
}

extern "C" void kernel_launch(void* const* d_in, const int* in_sizes, int n_in,
                              void* d_out, int out_size, void* d_ws, size_t ws_size,
                              hipStream_t stream) {
    const float* I = (const float*)d_in[0];   // y_true
    const float* J = (const float*)d_in[1];   // y_pred
    __half2* B = (__half2*)d_ws;               // 5*NH2 half2
    float* acc = (float*)(B + 5 * NH2);
    float* out = (float*)d_out;

    ncc_k1<<<(3 * D_ * 8 * WP_) / 256, 256, 0, stream>>>(I, J, B, acc);
    ncc_k2<<<(HWP_ / 256) * (D_ / CH3), 256, 0, stream>>>(B, acc);
    ncc_finalize<<<1, 1, 0, stream>>>(acc, out);
}